// Round 3
// baseline (162.202 us; speedup 1.0000x reference)
//
#include <hip/hip_runtime.h>

// TSA_24936580121000 — fused temporal self-attention, MI355X gfx950. Round 3.
// vs R2: (a) 8-deep batched global loads in the stage phase, (b) residual x
// kept in registers as bf16 (no phase-5 global re-read), (c) 256-thread
// blocks, WT=8, 35KiB LDS -> 4 blocks/CU for phase decorrelation.

#define C_  128
#define T_  16
#define H_  64
#define W_  64
#define HW_ (H_*W_)
#define CO_ 160          // 16 q + 16 k + 128 v
#define WT_ 8            // w positions per block
#define NBLK 2048        // 4 b * 64 h * 8 wtiles
#define THW (T_*H_*W_)

typedef float  f32x4  __attribute__((ext_vector_type(4)));
typedef short  bf16x4 __attribute__((ext_vector_type(4)));
typedef short  bf16x8 __attribute__((ext_vector_type(8)));

__device__ __forceinline__ unsigned short f2bf(float f) {
    union { float f; unsigned u; } v; v.f = f;
    unsigned r = v.u + 0x7fffu + ((v.u >> 16) & 1u);   // RNE
    return (unsigned short)(r >> 16);
}
__device__ __forceinline__ float bf2f(unsigned short s) {
    union { unsigned u; float f; } v; v.u = ((unsigned)s) << 16;
    return v.f;
}

// ---------------- prepack: fp32 weights -> bf16 W2[160][128], biases b2[160] ----
__global__ __launch_bounds__(256) void tsa_prepack(
        const float* __restrict__ qw, const float* __restrict__ qb,
        const float* __restrict__ kw, const float* __restrict__ kb,
        const float* __restrict__ vw, const float* __restrict__ vb,
        unsigned short* __restrict__ W2, float* __restrict__ b2) {
    int i = blockIdx.x * 256 + threadIdx.x;      // 80*256 == 20480 == 160*128
    int o = i >> 7, c = i & 127;
    float v = (o < 16) ? qw[o * C_ + c] : (o < 32) ? kw[(o - 16) * C_ + c]
                                                   : vw[(o - 32) * C_ + c];
    W2[i] = f2bf(v);
    if (i < CO_) b2[i] = (i < 16) ? qb[i] : (i < 32) ? kb[i - 16] : vb[i - 32];
}

// ---------------- LDS geometry (shorts) — ONE buffer, three time-shared views --
// x-stage:  [pos=8][t=16][c=128]  pos-stride PS=2184, t-stride TS=136 (17472 sh)
// qk:       [pos=8][2][t=16][o=16]                                    ( 4096 sh)
// out:      [t=16][w=8][c=128]    t-stride 1096, w-stride 136         (17536 sh)
#define PS 2184
#define TS 136
#define IDX_X(pos, t, c)      ((pos) * PS + (t) * TS + (c))
#define IDX_QK(pos, qk, t, o) (((((pos) * 2 + (qk)) * T_ + (t)) * 16) + (o))
#define OS_W 136
#define OS_T 1096
#define IDX_O(t, w, c)        ((t) * OS_T + (w) * OS_W + (c))
#define BUF_SH 17536          // 35072 B -> 4 blocks/CU

// ---------------- main fused kernel --------------------------------------------
__global__ __launch_bounds__(256, 4) void tsa_main(
        const float* __restrict__ x, const unsigned short* __restrict__ W2,
        const float* __restrict__ b2, const float* __restrict__ gamma,
        float* __restrict__ y) {

    __shared__ __align__(16) unsigned short buf[BUF_SH];

    // XCD-chunked swizzle (nwg=2048 % 8 == 0): the 8 wtiles of one (b,h) row
    // are consecutive on one XCD -> 32B-sector merge in that XCD's L2.
    int bid  = blockIdx.x;
    int work = (bid & 7) * (NBLK / 8) + (bid >> 3);
    int bh = work >> 3;                  // 0..255 = b*64 + h
    int wt = work & 7;
    int b  = bh >> 6, h = bh & 63;
    int w0 = wt * WT_;

    const size_t base = (size_t)b * C_ * THW + (size_t)h * W_ + w0;
    const float* xb = x + base;
    float*       yb = y + base;

    const int tid = threadIdx.x;
    const int seg = tid & 1;          // 16B segment within the 32B w-row
    const int cs  = tid >> 1;         // channel 0..127
    const float g = gamma[0];

    // ---- phase 1: stage x tile -> bf16 LDS [pos][t][c]; keep bf16 residual ---
    // All 16 loads issued in two 8-deep batches before any conversion.
    bf16x4 res[16];                   // residual x (bf16), lives to phase 5
    {
        const float* xcol = xb + (size_t)cs * THW + seg * 4;
        f32x4 xrA[8], xrB[8];
        #pragma unroll
        for (int t = 0; t < 8; ++t) xrA[t] = *(const f32x4*)(xcol + t * HW_);
        #pragma unroll
        for (int t = 0; t < 8; ++t) xrB[t] = *(const f32x4*)(xcol + (t + 8) * HW_);
        #pragma unroll
        for (int t = 0; t < 8; ++t) {
            #pragma unroll
            for (int e = 0; e < 4; ++e) {
                unsigned short u = f2bf(xrA[t][e]);
                res[t][e] = (short)u;
                buf[IDX_X(seg * 4 + e, t, cs)] = u;
            }
        }
        #pragma unroll
        for (int t = 0; t < 8; ++t) {
            #pragma unroll
            for (int e = 0; e < 4; ++e) {
                unsigned short u = f2bf(xrB[t][e]);
                res[t + 8][e] = (short)u;
                buf[IDX_X(seg * 4 + e, t + 8, cs)] = u;
            }
        }
    }

    const int wv  = tid >> 6;          // wave 0..3 -> positions wv*2, wv*2+1
    const int lr  = tid & 15;
    const int grp = (tid & 63) >> 4;

    float biasv[10];
    #pragma unroll
    for (int nt = 0; nt < 10; ++nt) biasv[nt] = b2[nt * 16 + lr];

    __syncthreads();   // B1: stage complete

    // ---- phase 2 pre: A-fragments (x[t][c]) to registers --------------------
    bf16x8 afrag[2][4];
    #pragma unroll
    for (int p = 0; p < 2; ++p)
        #pragma unroll
        for (int ks = 0; ks < 4; ++ks)
            afrag[p][ks] = *(const bf16x8*)&buf[IDX_X(wv * 2 + p, lr, ks * 32 + grp * 8)];

    __syncthreads();   // B1.5: qk region aliases x pos 0..1 — all reads done

    // ---- phase 2: qkv projection (mfma 16x16x32 bf16) -----------------------
    // v stays in registers: proj D-layout (col=o=lr, row=t=grp*4+r) IS the PV
    // A-layout (row=c=lr, k=j=grp*4+r) for the same lane.
    bf16x4 vreg[2][8];
    #pragma unroll
    for (int nt = 0; nt < 10; ++nt) {
        f32x4 acc0 = (f32x4){0.f, 0.f, 0.f, 0.f};
        f32x4 acc1 = (f32x4){0.f, 0.f, 0.f, 0.f};
        #pragma unroll
        for (int ks = 0; ks < 4; ++ks) {
            bf16x8 wf = *(const bf16x8*)&W2[(nt * 16 + lr) * C_ + ks * 32 + grp * 8];
            acc0 = __builtin_amdgcn_mfma_f32_16x16x32_bf16(afrag[0][ks], wf, acc0, 0, 0, 0);
            acc1 = __builtin_amdgcn_mfma_f32_16x16x32_bf16(afrag[1][ks], wf, acc1, 0, 0, 0);
        }
        if (nt < 2) {                 // q/k -> LDS (cross-lane transpose needed)
            #pragma unroll
            for (int r = 0; r < 4; ++r) {
                buf[IDX_QK(wv * 2 + 0, nt, grp * 4 + r, lr)] = f2bf(acc0[r] + biasv[nt]);
                buf[IDX_QK(wv * 2 + 1, nt, grp * 4 + r, lr)] = f2bf(acc1[r] + biasv[nt]);
            }
        } else {                      // v -> registers (bf16 packed)
            bf16x4 p0, p1;
            #pragma unroll
            for (int r = 0; r < 4; ++r) {
                p0[r] = (short)f2bf(acc0[r] + biasv[nt]);
                p1[r] = (short)f2bf(acc1[r] + biasv[nt]);
            }
            vreg[0][nt - 2] = p0;
            vreg[1][nt - 2] = p1;
        }
    }
    __syncthreads();   // B2: qk visible

    // ---- phase 3: scores^T -> softmax -> PV -> pack out bf16 ----------------
    bf16x4 obf[2][8];
    #pragma unroll
    for (int p = 0; p < 2; ++p) {
        int pos = wv * 2 + p;
        bf16x4 kf = *(const bf16x4*)&buf[IDX_QK(pos, 1, lr, grp * 4)];
        bf16x4 qf = *(const bf16x4*)&buf[IDX_QK(pos, 0, lr, grp * 4)];
        f32x4 s = (f32x4){0.f, 0.f, 0.f, 0.f};
        s = __builtin_amdgcn_mfma_f32_16x16x16bf16_1k(kf, qf, s, 0, 0, 0);
        float mx = fmaxf(fmaxf(s[0], s[1]), fmaxf(s[2], s[3]));
        mx = fmaxf(mx, __shfl_xor(mx, 16));
        mx = fmaxf(mx, __shfl_xor(mx, 32));
        float e0 = __expf(s[0] - mx), e1 = __expf(s[1] - mx);
        float e2 = __expf(s[2] - mx), e3 = __expf(s[3] - mx);
        float sm = e0 + e1 + e2 + e3;
        sm += __shfl_xor(sm, 16);
        sm += __shfl_xor(sm, 32);
        float inv = 1.0f / sm;
        bf16x4 pf;
        pf[0] = (short)f2bf(e0 * inv); pf[1] = (short)f2bf(e1 * inv);
        pf[2] = (short)f2bf(e2 * inv); pf[3] = (short)f2bf(e3 * inv);
        #pragma unroll
        for (int ct = 0; ct < 8; ++ct) {
            f32x4 z = (f32x4){0.f, 0.f, 0.f, 0.f};
            z = __builtin_amdgcn_mfma_f32_16x16x16bf16_1k(vreg[p][ct], pf, z, 0, 0, 0);
            bf16x4 ob;
            #pragma unroll
            for (int r = 0; r < 4; ++r) ob[r] = (short)f2bf(z[r]);
            obf[p][ct] = ob;
        }
    }
    __syncthreads();   // B3: qk reads done — buffer becomes out region

    // ---- phase 4: spill outT -> LDS [t][w][c] -------------------------------
    #pragma unroll
    for (int p = 0; p < 2; ++p)
        #pragma unroll
        for (int ct = 0; ct < 8; ++ct)
            *(bf16x4*)&buf[IDX_O(lr, wv * 2 + p, ct * 16 + grp * 4)] = obf[p][ct];
    __syncthreads();   // B4

    // ---- phase 5: y = gamma*out + res, NO global reads ----------------------
    {
        float* yrow = yb + (size_t)cs * THW + seg * 4;
        #pragma unroll
        for (int t = 0; t < T_; ++t) {
            f32x4 rv;
            #pragma unroll
            for (int e = 0; e < 4; ++e)
                rv[e] = fmaf(g, bf2f(buf[IDX_O(t, seg * 4 + e, cs)]),
                             bf2f((unsigned short)res[t][e]));
            *(f32x4*)(yrow + t * HW_) = rv;
        }
    }
}

// ---------------- launch --------------------------------------------------------
extern "C" void kernel_launch(void* const* d_in, const int* in_sizes, int n_in,
                              void* d_out, int out_size, void* d_ws, size_t ws_size,
                              hipStream_t stream) {
    const float* x  = (const float*)d_in[0];
    const float* qw = (const float*)d_in[1];
    const float* qb = (const float*)d_in[2];
    const float* kw = (const float*)d_in[3];
    const float* kb = (const float*)d_in[4];
    const float* vw = (const float*)d_in[5];
    const float* vb = (const float*)d_in[6];
    const float* gm = (const float*)d_in[7];
    float* y = (float*)d_out;

    unsigned short* W2 = (unsigned short*)d_ws;                  // 160*128 bf16
    float* b2 = (float*)((char*)d_ws + CO_ * C_ * sizeof(unsigned short));

    tsa_prepack<<<80, 256, 0, stream>>>(qw, qb, kw, kb, vw, vb, W2, b2);
    tsa_main<<<NBLK, 256, 0, stream>>>(x, W2, b2, gm, y);
}

// Round 4
// 146.977 us; speedup vs baseline: 1.1036x; 1.1036x over previous
//
#include <hip/hip_runtime.h>

// TSA_24936580121000 — fused temporal self-attention, MI355X gfx950. Round 4.
// vs R3: WT=32 (128B contiguous pieces per (c,t) for both read and write —
// probing the 64B-sector granularity wall), 1024 threads, 1 block/CU,
// stage-LDS c-XOR swizzle (conflict-free stage writes), WRITE_SIZE back to 1x.

#define C_  128
#define T_  16
#define H_  64
#define W_  64
#define HW_ (H_*W_)
#define CO_ 160          // 16 q + 16 k + 128 v
#define WT_ 32           // w positions per block
#define NBLK 512         // 4 b * 64 h * 2 wtiles
#define THW (T_*H_*W_)

typedef float  f32x4  __attribute__((ext_vector_type(4)));
typedef short  bf16x4 __attribute__((ext_vector_type(4)));
typedef short  bf16x8 __attribute__((ext_vector_type(8)));

__device__ __forceinline__ unsigned short f2bf(float f) {
    union { float f; unsigned u; } v; v.f = f;
    unsigned r = v.u + 0x7fffu + ((v.u >> 16) & 1u);   // RNE
    return (unsigned short)(r >> 16);
}
__device__ __forceinline__ float bf2f(unsigned short s) {
    union { unsigned u; float f; } v; v.u = ((unsigned)s) << 16;
    return v.f;
}

// ---------------- prepack: fp32 weights -> bf16 W2[160][128], biases b2[160] ----
__global__ __launch_bounds__(256) void tsa_prepack(
        const float* __restrict__ qw, const float* __restrict__ qb,
        const float* __restrict__ kw, const float* __restrict__ kb,
        const float* __restrict__ vw, const float* __restrict__ vb,
        unsigned short* __restrict__ W2, float* __restrict__ b2) {
    int i = blockIdx.x * 256 + threadIdx.x;      // 80*256 == 20480 == 160*128
    int o = i >> 7, c = i & 127;
    float v = (o < 16) ? qw[o * C_ + c] : (o < 32) ? kw[(o - 16) * C_ + c]
                                                   : vw[(o - 32) * C_ + c];
    W2[i] = f2bf(v);
    if (i < CO_) b2[i] = (i < 16) ? qb[i] : (i < 32) ? kb[i - 16] : vb[i - 32];
}

// ---------------- LDS geometry (shorts) — ONE buffer, three time-shared views --
// x-stage: [pos=32][t=16][c=128]  pos-stride PS=2184, t-stride TS=136.
//          c stored XOR-swizzled: loc_c = c ^ ((pos>>2)<<3)  (keeps 8-contig).
// qk:      [pos=32][2][t=16][o=16] = 16384 sh, aliases stage pos 0..7 region.
// out:     [t=16][w=32][c=128]    t-stride 4232, w-stride 132 (no swizzle).
#define PS 2184
#define TS 136
#define IDX_XS(pos, t, loc)   ((pos) * PS + (t) * TS + (loc))
#define IDX_QK(pos, qk, t, o) (((((pos) * 2 + (qk)) * T_ + (t)) * 16) + (o))
#define OS_W 132
#define OS_T 4232
#define IDX_O(t, w, c)        ((t) * OS_T + (w) * OS_W + (c))
#define BUF_SH (WT_ * PS)     // 69888 shorts = 139776 B -> 1 block/CU

// ---------------- main fused kernel --------------------------------------------
__global__ __launch_bounds__(1024, 4) void tsa_main(
        const float* __restrict__ x, const unsigned short* __restrict__ W2,
        const float* __restrict__ b2, const float* __restrict__ gamma,
        float* __restrict__ y) {

    __shared__ __align__(16) unsigned short buf[BUF_SH];

    // XCD-chunked swizzle (nwg=512 % 8 == 0): the 2 wtiles of one (b,h) row are
    // consecutive on one XCD -> adjacent 128B pieces merge toward 256B at DRAM.
    int bid  = blockIdx.x;
    int work = (bid & 7) * (NBLK / 8) + (bid >> 3);
    int bh = work >> 1;                  // 0..255 = b*64 + h
    int wt = work & 1;
    int b  = bh >> 6, h = bh & 63;
    int w0 = wt * WT_;

    const size_t base = (size_t)b * C_ * THW + (size_t)h * W_ + w0;
    const float* xb = x + base;
    float*       yb = y + base;

    const int tid = threadIdx.x;
    const int seg = tid & 7;          // 16B segment within the 128B w-row
    const int cs  = tid >> 3;         // channel 0..127
    const float g = gamma[0];

    // ---- phase 1: stage x tile -> bf16 LDS [pos][t][c-swz]; keep bf16 residual
    // Per wave-instr: 8 channels x 128B fully-used contiguous pieces.
    bf16x4 res[16];                   // residual x (bf16), lives to phase 5
    {
        const float* xcol = xb + (size_t)cs * THW + seg * 4;
        const int loc = cs ^ (seg << 3);     // pos>>2 == seg for pos=seg*4+e
        f32x4 xrA[8], xrB[8];
        #pragma unroll
        for (int t = 0; t < 8; ++t) xrA[t] = *(const f32x4*)(xcol + t * HW_);
        #pragma unroll
        for (int t = 0; t < 8; ++t) xrB[t] = *(const f32x4*)(xcol + (t + 8) * HW_);
        #pragma unroll
        for (int t = 0; t < 8; ++t) {
            #pragma unroll
            for (int e = 0; e < 4; ++e) {
                unsigned short u = f2bf(xrA[t][e]);
                res[t][e] = (short)u;
                buf[IDX_XS(seg * 4 + e, t, loc)] = u;
            }
        }
        #pragma unroll
        for (int t = 0; t < 8; ++t) {
            #pragma unroll
            for (int e = 0; e < 4; ++e) {
                unsigned short u = f2bf(xrB[t][e]);
                res[t + 8][e] = (short)u;
                buf[IDX_XS(seg * 4 + e, t + 8, loc)] = u;
            }
        }
    }

    const int wv  = tid >> 6;          // wave 0..15 -> positions wv*2, wv*2+1
    const int lr  = tid & 15;
    const int grp = (tid & 63) >> 4;

    float biasv[10];
    #pragma unroll
    for (int nt = 0; nt < 10; ++nt) biasv[nt] = b2[nt * 16 + lr];

    __syncthreads();   // B1: stage complete

    // ---- phase 2 pre: A-fragments (x[t][c]) to registers --------------------
    bf16x8 afrag[2][4];
    #pragma unroll
    for (int p = 0; p < 2; ++p) {
        int pos = wv * 2 + p;
        int sw  = (pos >> 2) << 3;
        #pragma unroll
        for (int ks = 0; ks < 4; ++ks)
            afrag[p][ks] = *(const bf16x8*)&buf[IDX_XS(pos, lr, (ks * 32 + grp * 8) ^ sw)];
    }

    __syncthreads();   // B1.5: qk region aliases stage pos 0..7 — all reads done

    // ---- phase 2: qkv projection (mfma 16x16x32 bf16) -----------------------
    // v stays in registers: proj D-layout (col=o=lr, row=t=grp*4+r) IS the PV
    // A-layout (row=c=lr, k=j=grp*4+r) for the same lane.
    bf16x4 vreg[2][8];
    #pragma unroll
    for (int nt = 0; nt < 10; ++nt) {
        f32x4 acc0 = (f32x4){0.f, 0.f, 0.f, 0.f};
        f32x4 acc1 = (f32x4){0.f, 0.f, 0.f, 0.f};
        #pragma unroll
        for (int ks = 0; ks < 4; ++ks) {
            bf16x8 wf = *(const bf16x8*)&W2[(nt * 16 + lr) * C_ + ks * 32 + grp * 8];
            acc0 = __builtin_amdgcn_mfma_f32_16x16x32_bf16(afrag[0][ks], wf, acc0, 0, 0, 0);
            acc1 = __builtin_amdgcn_mfma_f32_16x16x32_bf16(afrag[1][ks], wf, acc1, 0, 0, 0);
        }
        if (nt < 2) {                 // q/k -> LDS (cross-lane transpose needed)
            #pragma unroll
            for (int r = 0; r < 4; ++r) {
                buf[IDX_QK(wv * 2 + 0, nt, grp * 4 + r, lr)] = f2bf(acc0[r] + biasv[nt]);
                buf[IDX_QK(wv * 2 + 1, nt, grp * 4 + r, lr)] = f2bf(acc1[r] + biasv[nt]);
            }
        } else {                      // v -> registers (bf16 packed)
            bf16x4 p0, p1;
            #pragma unroll
            for (int r = 0; r < 4; ++r) {
                p0[r] = (short)f2bf(acc0[r] + biasv[nt]);
                p1[r] = (short)f2bf(acc1[r] + biasv[nt]);
            }
            vreg[0][nt - 2] = p0;
            vreg[1][nt - 2] = p1;
        }
    }
    __syncthreads();   // B2: qk visible

    // ---- phase 3: scores^T -> softmax -> PV -> pack out bf16 ----------------
    bf16x4 obf[2][8];
    #pragma unroll
    for (int p = 0; p < 2; ++p) {
        int pos = wv * 2 + p;
        bf16x4 kf = *(const bf16x4*)&buf[IDX_QK(pos, 1, lr, grp * 4)];
        bf16x4 qf = *(const bf16x4*)&buf[IDX_QK(pos, 0, lr, grp * 4)];
        f32x4 s = (f32x4){0.f, 0.f, 0.f, 0.f};
        s = __builtin_amdgcn_mfma_f32_16x16x16bf16_1k(kf, qf, s, 0, 0, 0);
        float mx = fmaxf(fmaxf(s[0], s[1]), fmaxf(s[2], s[3]));
        mx = fmaxf(mx, __shfl_xor(mx, 16));
        mx = fmaxf(mx, __shfl_xor(mx, 32));
        float e0 = __expf(s[0] - mx), e1 = __expf(s[1] - mx);
        float e2 = __expf(s[2] - mx), e3 = __expf(s[3] - mx);
        float sm = e0 + e1 + e2 + e3;
        sm += __shfl_xor(sm, 16);
        sm += __shfl_xor(sm, 32);
        float inv = 1.0f / sm;
        bf16x4 pf;
        pf[0] = (short)f2bf(e0 * inv); pf[1] = (short)f2bf(e1 * inv);
        pf[2] = (short)f2bf(e2 * inv); pf[3] = (short)f2bf(e3 * inv);
        #pragma unroll
        for (int ct = 0; ct < 8; ++ct) {
            f32x4 z = (f32x4){0.f, 0.f, 0.f, 0.f};
            z = __builtin_amdgcn_mfma_f32_16x16x16bf16_1k(vreg[p][ct], pf, z, 0, 0, 0);
            bf16x4 ob;
            #pragma unroll
            for (int r = 0; r < 4; ++r) ob[r] = (short)f2bf(z[r]);
            obf[p][ct] = ob;
        }
    }
    __syncthreads();   // B3: qk/stage reads done — buffer becomes out region

    // ---- phase 4: spill outT -> LDS [t][w][c] -------------------------------
    #pragma unroll
    for (int p = 0; p < 2; ++p)
        #pragma unroll
        for (int ct = 0; ct < 8; ++ct)
            *(bf16x4*)&buf[IDX_O(lr, wv * 2 + p, ct * 16 + grp * 4)] = obf[p][ct];
    __syncthreads();   // B4

    // ---- phase 5: y = gamma*out + res, NO global reads; 128B write pieces ---
    {
        float* yrow = yb + (size_t)cs * THW + seg * 4;
        #pragma unroll
        for (int t = 0; t < T_; ++t) {
            f32x4 rv;
            #pragma unroll
            for (int e = 0; e < 4; ++e)
                rv[e] = fmaf(g, bf2f(buf[IDX_O(t, seg * 4 + e, cs)]),
                             bf2f((unsigned short)res[t][e]));
            *(f32x4*)(yrow + t * HW_) = rv;
        }
    }
}

// ---------------- launch --------------------------------------------------------
extern "C" void kernel_launch(void* const* d_in, const int* in_sizes, int n_in,
                              void* d_out, int out_size, void* d_ws, size_t ws_size,
                              hipStream_t stream) {
    const float* x  = (const float*)d_in[0];
    const float* qw = (const float*)d_in[1];
    const float* qb = (const float*)d_in[2];
    const float* kw = (const float*)d_in[3];
    const float* kb = (const float*)d_in[4];
    const float* vw = (const float*)d_in[5];
    const float* vb = (const float*)d_in[6];
    const float* gm = (const float*)d_in[7];
    float* y = (float*)d_out;

    unsigned short* W2 = (unsigned short*)d_ws;                  // 160*128 bf16
    float* b2 = (float*)((char*)d_ws + CO_ * C_ * sizeof(unsigned short));

    tsa_prepack<<<80, 256, 0, stream>>>(qw, qb, kw, kb, vw, vb, W2, b2);
    tsa_main<<<NBLK, 1024, 0, stream>>>(x, W2, b2, gm, y);
}

// Round 5
// 141.713 us; speedup vs baseline: 1.1446x; 1.0371x over previous
//
#include <hip/hip_runtime.h>

// TSA_24936580121000 — fused temporal self-attention, MI355X gfx950. Round 5.
// R2 structure (WT=16, 512 thr, 70KiB LDS, 2 blocks/CU, clean HBM traffic)
// + latency fixes with TRANSIENT-only register use (R3/R4 regressed via VGPR
// spill: long-lived arrays over the 64/128 allocator quantum -> scratch):
//   (1) 8-deep batched stage loads
//   (2) W2 B-fragment prefetch (nt=0 issued before B1; steady depth-1)
//   (3) phase-5 x re-reads pre-issued before/around the P4 spill barriers

#define C_  128
#define T_  16
#define H_  64
#define W_  64
#define HW_ (H_*W_)
#define CO_ 160          // 16 q + 16 k + 128 v
#define WT_ 16           // w positions per block
#define NBLK 1024        // 4 b * 64 h * 4 wtiles
#define THW (T_*H_*W_)

typedef float  f32x4  __attribute__((ext_vector_type(4)));
typedef short  bf16x4 __attribute__((ext_vector_type(4)));
typedef short  bf16x8 __attribute__((ext_vector_type(8)));

__device__ __forceinline__ unsigned short f2bf(float f) {
    union { float f; unsigned u; } v; v.f = f;
    unsigned r = v.u + 0x7fffu + ((v.u >> 16) & 1u);   // RNE
    return (unsigned short)(r >> 16);
}
__device__ __forceinline__ float bf2f(unsigned short s) {
    union { unsigned u; float f; } v; v.u = ((unsigned)s) << 16;
    return v.f;
}

// ---------------- prepack: fp32 weights -> bf16 W2[160][128], biases b2[160] ----
__global__ __launch_bounds__(256) void tsa_prepack(
        const float* __restrict__ qw, const float* __restrict__ qb,
        const float* __restrict__ kw, const float* __restrict__ kb,
        const float* __restrict__ vw, const float* __restrict__ vb,
        unsigned short* __restrict__ W2, float* __restrict__ b2) {
    int i = blockIdx.x * 256 + threadIdx.x;      // 80*256 == 20480 == 160*128
    int o = i >> 7, c = i & 127;
    float v = (o < 16) ? qw[o * C_ + c] : (o < 32) ? kw[(o - 16) * C_ + c]
                                                   : vw[(o - 32) * C_ + c];
    W2[i] = f2bf(v);
    if (i < CO_) b2[i] = (i < 16) ? qb[i] : (i < 32) ? kb[i - 16] : vb[i - 32];
}

// ---------------- LDS geometry (shorts) — ONE buffer, three time-shared views --
// x-stage:  [pos=16][t=16][c=128]  pos-stride PS=2184, t-stride TS=136 (34944 sh)
// qk:       [pos=16][2][t=16][o=16] = 8192 sh (aliases stage pos 0..3 region)
// out:      [t=16][w=16][c=128]    t-stride 2116, w-stride 132        (33856 sh)
#define PS 2184
#define TS 136
#define IDX_X(pos, t, c)      ((pos) * PS + (t) * TS + (c))
#define IDX_QK(pos, qk, t, o) (((((pos) * 2 + (qk)) * T_ + (t)) * 16) + (o))
#define OS_W 132
#define OS_T 2116
#define IDX_O(t, w, c)        ((t) * OS_T + (w) * OS_W + (c))
#define BUF_SH (T_ * PS)      // 34944 shorts = 69888 B -> 2 blocks/CU

// ---------------- main fused kernel --------------------------------------------
__global__ __launch_bounds__(512, 4) void tsa_main(
        const float* __restrict__ x, const unsigned short* __restrict__ W2,
        const float* __restrict__ b2, const float* __restrict__ gamma,
        float* __restrict__ y) {

    __shared__ __align__(16) unsigned short buf[BUF_SH];

    // XCD-chunked swizzle (nwg=1024 % 8 == 0): 4 wtiles of one (b,h) row share an XCD.
    int bid  = blockIdx.x;
    int work = (bid & 7) * (NBLK / 8) + (bid >> 3);
    int bh = work >> 2;
    int wt = work & 3;
    int b  = bh >> 6, h = bh & 63;
    int w0 = wt * WT_;

    const size_t base = (size_t)b * C_ * THW + (size_t)h * W_ + w0;
    const float* xb = x + base;
    float*       yb = y + base;

    const int tid = threadIdx.x;
    const int wq  = tid & 3;          // 16B segment within the 64B w-row
    const int cs  = tid >> 2;         // channel 0..127
    const float g = gamma[0];

    const int wv  = tid >> 6;         // wave 0..7 -> positions wv*2, wv*2+1
    const int lr  = tid & 15;
    const int grp = (tid & 63) >> 4;

    // ---- phase 1: stage x tile -> bf16 LDS [pos][t][c], 8-deep batches ------
    // Also pre-issue nt=0 weight frags + biases so they fly during B1.
    bf16x8 wfC[4];
    float biasv[10];
    {
        const float* xcol = xb + (size_t)cs * THW + wq * 4;
        f32x4 xrA[8];
        #pragma unroll
        for (int t = 0; t < 8; ++t) xrA[t] = *(const f32x4*)(xcol + t * HW_);
        #pragma unroll
        for (int ks = 0; ks < 4; ++ks)
            wfC[ks] = *(const bf16x8*)&W2[lr * C_ + ks * 32 + grp * 8];
        #pragma unroll
        for (int nt = 0; nt < 10; ++nt) biasv[nt] = b2[nt * 16 + lr];
        #pragma unroll
        for (int t = 0; t < 8; ++t) {
            #pragma unroll
            for (int e = 0; e < 4; ++e)
                buf[IDX_X(wq * 4 + e, t, cs)] = f2bf(xrA[t][e]);
        }
        f32x4 xrB[8];
        #pragma unroll
        for (int t = 0; t < 8; ++t) xrB[t] = *(const f32x4*)(xcol + (t + 8) * HW_);
        #pragma unroll
        for (int t = 0; t < 8; ++t) {
            #pragma unroll
            for (int e = 0; e < 4; ++e)
                buf[IDX_X(wq * 4 + e, t + 8, cs)] = f2bf(xrB[t][e]);
        }
    }
    __syncthreads();   // B1: stage complete (wfC/biasv latency hidden here)

    // ---- phase 2 pre: A-fragments (x[t][c]) to registers --------------------
    bf16x8 afrag[2][4];
    #pragma unroll
    for (int p = 0; p < 2; ++p)
        #pragma unroll
        for (int ks = 0; ks < 4; ++ks)
            afrag[p][ks] = *(const bf16x8*)&buf[IDX_X(wv * 2 + p, lr, ks * 32 + grp * 8)];

    __syncthreads();   // B1.5: qk region aliases stage pos 0..3 — all reads done

    // ---- phase 2: qkv projection (mfma 16x16x32 bf16), W2 prefetch depth-1 --
    // v stays in registers: proj D-layout (col=o=lr, row=t=grp*4+r) IS the PV
    // A-layout (row=c=lr, k=j=grp*4+r) for the same lane.
    bf16x4 vreg[2][8];
    #pragma unroll
    for (int nt = 0; nt < 10; ++nt) {
        bf16x8 wfN[4];
        if (nt < 9) {
            #pragma unroll
            for (int ks = 0; ks < 4; ++ks)
                wfN[ks] = *(const bf16x8*)&W2[((nt + 1) * 16 + lr) * C_ + ks * 32 + grp * 8];
        }
        f32x4 acc0 = (f32x4){0.f, 0.f, 0.f, 0.f};
        f32x4 acc1 = (f32x4){0.f, 0.f, 0.f, 0.f};
        #pragma unroll
        for (int ks = 0; ks < 4; ++ks) {
            acc0 = __builtin_amdgcn_mfma_f32_16x16x32_bf16(afrag[0][ks], wfC[ks], acc0, 0, 0, 0);
            acc1 = __builtin_amdgcn_mfma_f32_16x16x32_bf16(afrag[1][ks], wfC[ks], acc1, 0, 0, 0);
        }
        if (nt < 2) {                 // q/k -> LDS (cross-lane transpose needed)
            #pragma unroll
            for (int r = 0; r < 4; ++r) {
                buf[IDX_QK(wv * 2 + 0, nt, grp * 4 + r, lr)] = f2bf(acc0[r] + biasv[nt]);
                buf[IDX_QK(wv * 2 + 1, nt, grp * 4 + r, lr)] = f2bf(acc1[r] + biasv[nt]);
            }
        } else {                      // v -> registers (bf16 packed)
            bf16x4 p0, p1;
            #pragma unroll
            for (int r = 0; r < 4; ++r) {
                p0[r] = (short)f2bf(acc0[r] + biasv[nt]);
                p1[r] = (short)f2bf(acc1[r] + biasv[nt]);
            }
            vreg[0][nt - 2] = p0;
            vreg[1][nt - 2] = p1;
        }
        #pragma unroll
        for (int ks = 0; ks < 4; ++ks) wfC[ks] = wfN[ks];
    }
    __syncthreads();   // B2: qk visible

    // ---- phase 3: scores^T -> softmax -> PV -> pack out bf16 ----------------
    bf16x4 obf[2][8];
    #pragma unroll
    for (int p = 0; p < 2; ++p) {
        int pos = wv * 2 + p;
        bf16x4 kf = *(const bf16x4*)&buf[IDX_QK(pos, 1, lr, grp * 4)];
        bf16x4 qf = *(const bf16x4*)&buf[IDX_QK(pos, 0, lr, grp * 4)];
        f32x4 s = (f32x4){0.f, 0.f, 0.f, 0.f};
        s = __builtin_amdgcn_mfma_f32_16x16x16bf16_1k(kf, qf, s, 0, 0, 0);
        float mx = fmaxf(fmaxf(s[0], s[1]), fmaxf(s[2], s[3]));
        mx = fmaxf(mx, __shfl_xor(mx, 16));
        mx = fmaxf(mx, __shfl_xor(mx, 32));
        float e0 = __expf(s[0] - mx), e1 = __expf(s[1] - mx);
        float e2 = __expf(s[2] - mx), e3 = __expf(s[3] - mx);
        float sm = e0 + e1 + e2 + e3;
        sm += __shfl_xor(sm, 16);
        sm += __shfl_xor(sm, 32);
        float inv = 1.0f / sm;
        bf16x4 pf;
        pf[0] = (short)f2bf(e0 * inv); pf[1] = (short)f2bf(e1 * inv);
        pf[2] = (short)f2bf(e2 * inv); pf[3] = (short)f2bf(e3 * inv);
        #pragma unroll
        for (int ct = 0; ct < 8; ++ct) {
            f32x4 z = (f32x4){0.f, 0.f, 0.f, 0.f};
            z = __builtin_amdgcn_mfma_f32_16x16x16bf16_1k(vreg[p][ct], pf, z, 0, 0, 0);
            bf16x4 ob;
            #pragma unroll
            for (int r = 0; r < 4; ++r) ob[r] = (short)f2bf(z[r]);
            obf[p][ct] = ob;
        }
    }
    __syncthreads();   // B3: qk/stage reads done — buffer becomes out region

    // ---- phase 4: pre-issue first half of x re-reads, then spill outT -------
    const float* xrow = xb + (size_t)cs * THW + wq * 4;
    f32x4 xpA[8];
    #pragma unroll
    for (int t = 0; t < 8; ++t) xpA[t] = *(const f32x4*)(xrow + t * HW_);

    #pragma unroll
    for (int p = 0; p < 2; ++p)
        #pragma unroll
        for (int ct = 0; ct < 8; ++ct)
            *(bf16x4*)&buf[IDX_O(lr, wv * 2 + p, ct * 16 + grp * 4)] = obf[p][ct];
    __syncthreads();   // B4

    // ---- phase 5: y = gamma*out + x (exact fp32 residual), no stalls --------
    {
        float* yrow = yb + (size_t)cs * THW + wq * 4;
        f32x4 xpB[8];
        #pragma unroll
        for (int t = 0; t < 8; ++t) xpB[t] = *(const f32x4*)(xrow + (t + 8) * HW_);
        #pragma unroll
        for (int t = 0; t < 8; ++t) {
            f32x4 rv;
            #pragma unroll
            for (int e = 0; e < 4; ++e)
                rv[e] = fmaf(g, bf2f(buf[IDX_O(t, wq * 4 + e, cs)]), xpA[t][e]);
            *(f32x4*)(yrow + t * HW_) = rv;
        }
        #pragma unroll
        for (int t = 0; t < 8; ++t) {
            f32x4 rv;
            #pragma unroll
            for (int e = 0; e < 4; ++e)
                rv[e] = fmaf(g, bf2f(buf[IDX_O(t + 8, wq * 4 + e, cs)]), xpB[t][e]);
            *(f32x4*)(yrow + (t + 8) * HW_) = rv;
        }
    }
}

// ---------------- launch --------------------------------------------------------
extern "C" void kernel_launch(void* const* d_in, const int* in_sizes, int n_in,
                              void* d_out, int out_size, void* d_ws, size_t ws_size,
                              hipStream_t stream) {
    const float* x  = (const float*)d_in[0];
    const float* qw = (const float*)d_in[1];
    const float* qb = (const float*)d_in[2];
    const float* kw = (const float*)d_in[3];
    const float* kb = (const float*)d_in[4];
    const float* vw = (const float*)d_in[5];
    const float* vb = (const float*)d_in[6];
    const float* gm = (const float*)d_in[7];
    float* y = (float*)d_out;

    unsigned short* W2 = (unsigned short*)d_ws;                  // 160*128 bf16
    float* b2 = (float*)((char*)d_ws + CO_ * C_ * sizeof(unsigned short));

    tsa_prepack<<<80, 256, 0, stream>>>(qw, qb, kw, kb, vw, vb, W2, b2);
    tsa_main<<<NBLK, 512, 0, stream>>>(x, W2, b2, gm, y);
}